// Round 2
// baseline (171.401 us; speedup 1.0000x reference)
//
#include <hip/hip_runtime.h>

#define N_NODES 50000
#define N_EDGES 800000
#define E_TOT   850000          // edges + self loops
#define HD      256             // HEADS*HEAD_DIM
#define MAXDEG  64              // max in-degree ~45 (Poisson(17), fixed seed); P(>=64)~1e-19
#define NEG_SLOPE 0.2f
#define EPS 1e-16f

// ---- dst-bucket binning (kills the 16x scattered-write amplification) ----
#define NB     98               // buckets of 512 nodes (49999>>9 = 97)
#define BSHIFT 9
#define CAP    10240            // per-bucket arena cap: E[8704] + 16 sigma
#define ABLK   392              // binning blocks
#define EPB    2304             // edges per block (9/thread); 392*2304 >= 850000

typedef __attribute__((ext_vector_type(8))) short short8;
typedef __attribute__((ext_vector_type(4))) float f32x4;

__device__ __forceinline__ unsigned short f2bf(float f) {   // round-to-nearest-even
    union { float f; unsigned int i; } c; c.f = f;
    unsigned int r = 0x7fffu + ((c.i >> 16) & 1u);
    return (unsigned short)((c.i + r) >> 16);
}
__device__ __forceinline__ float bf2f(unsigned short u) {
    union { unsigned int i; float f; } c; c.i = ((unsigned int)u) << 16;
    return c.f;
}
__device__ __forceinline__ short8 pack8(float4 a, float4 b) {
    short8 r;
    r[0] = (short)f2bf(a.x); r[1] = (short)f2bf(a.y);
    r[2] = (short)f2bf(a.z); r[3] = (short)f2bf(a.w);
    r[4] = (short)f2bf(b.x); r[5] = (short)f2bf(b.y);
    r[6] = (short)f2bf(b.z); r[7] = (short)f2bf(b.w);
    return r;
}
__device__ __forceinline__ float lrelu_exp(float v) {
    v = (v < 0.f) ? v * NEG_SLOPE : v;
    return __expf(v);
}

// ws[k][head] = sum_j W[k][head*64+j]*att_src[head][j]  (attention folded into x-space)
__global__ __launch_bounds__(256) void prep_kernel(
        const float* __restrict__ W, const float* __restrict__ att_src,
        const float* __restrict__ att_dst, float* __restrict__ ws, float* __restrict__ wd) {
    const int t = threadIdx.x, head = t >> 6, k = t & 63;
    const float* wrow = W + k * 256 + head * 64;
    const float* as = att_src + head * 64;
    const float* adv = att_dst + head * 64;
    float s = 0.f, d = 0.f;
#pragma unroll 8
    for (int j = 0; j < 64; ++j) { s += wrow[j] * as[j]; d += wrow[j] * adv[j]; }
    ws[k * 4 + head] = s;
    wd[k * 4 + head] = d;
}

// Phase A: bin edges by dst>>9 into per-bucket arenas (L2-merged contiguous
// windows). Blocks 0..195 also compute per-node logits AND emit xb (bf16 copy
// of x) so the aggregate gather reads 128B/edge instead of 256B.
__global__ __launch_bounds__(256) void bin_logit_kernel(
        const float* __restrict__ x,
        const float4* __restrict__ ws4, const float4* __restrict__ wd4,
        const int* __restrict__ eidx,
        int* __restrict__ gcnt, unsigned int* __restrict__ arena,
        float4* __restrict__ a_src4, float4* __restrict__ a_dst4,
        unsigned short* __restrict__ xb) {
    __shared__ int hist[NB];
    __shared__ int abase[NB];
    const int t = threadIdx.x;
    const int e0 = blockIdx.x * EPB;
    if (t < NB) hist[t] = 0;
    __syncthreads();

    // pass 1: dst histogram
#pragma unroll
    for (int k = 0; k < EPB / 256; ++k) {
        const int g = e0 + k * 256 + t;
        if (g < E_TOT) {
            const int d = (g < N_EDGES) ? eidx[N_EDGES + g] : g - N_EDGES;
            atomicAdd(&hist[d >> BSHIFT], 1);
        }
    }
    __syncthreads();
    if (t < NB) {
        const int c = hist[t];
        abase[t] = c ? atomicAdd(&gcnt[t], c) : 0;
        hist[t] = 0;                                        // reuse as cursor
    }
    __syncthreads();

    // pass 2: scatter packed (src | dst_local<<16) pairs (dst row L2-hot)
#pragma unroll
    for (int k = 0; k < EPB / 256; ++k) {
        const int g = e0 + k * 256 + t;
        if (g < E_TOT) {
            int s, d;
            if (g < N_EDGES) { s = eidx[g]; d = eidx[N_EDGES + g]; }
            else             { s = d = g - N_EDGES; }
            const int b = d >> BSHIFT;
            const int pos = abase[b] + atomicAdd(&hist[b], 1);
            if (pos < CAP)
                arena[b * CAP + pos] =
                    (unsigned int)s | ((unsigned int)(d & 511) << 16);
        }
    }

    // per-node logits + bf16 x emission (x row already in registers)
    const int g = blockIdx.x * 256 + t;
    if (g < N_NODES) {
        const float4* xr = (const float4*)(x + (size_t)g * 64);
        float4 vs = {0.f, 0.f, 0.f, 0.f};
        float4 vd = {0.f, 0.f, 0.f, 0.f};
#pragma unroll 4
        for (int kk = 0; kk < 16; kk += 2) {
            float4 xv0 = xr[kk];
            float4 xv1 = xr[kk + 1];
            *(short8*)&xb[(size_t)g * 64 + kk * 4] = pack8(xv0, xv1);
#pragma unroll
            for (int j = 0; j < 8; ++j) {
                const float4 xv = (j < 4) ? xv0 : xv1;
                const int jj = j & 3;
                const float xj = jj == 0 ? xv.x : jj == 1 ? xv.y : jj == 2 ? xv.z : xv.w;
                const float4 w1 = ws4[(kk + (j >> 2)) * 4 + jj];
                const float4 w2 = wd4[(kk + (j >> 2)) * 4 + jj];
                vs.x += xj * w1.x; vs.y += xj * w1.y; vs.z += xj * w1.z; vs.w += xj * w1.w;
                vd.x += xj * w2.x; vd.y += xj * w2.y; vd.z += xj * w2.z; vd.w += xj * w2.w;
            }
        }
        a_src4[g] = vs;
        a_dst4[g] = vd;
    }
}

// Phase B: block b exclusively owns nodes [b*512, b*512+512) -> ELL build with
// LDS counters; scattered ushort writes stay in a private 64KB L2-hot window.
__global__ __launch_bounds__(512) void ell_build_kernel(
        const int* __restrict__ gcnt, const unsigned int* __restrict__ arena,
        int* __restrict__ cnt, unsigned short* __restrict__ slotu) {
    __shared__ int lcnt[512];
    const int t = threadIdx.x;
    const int b = blockIdx.x;
    lcnt[t] = 0;
    __syncthreads();
    int m = gcnt[b]; if (m > CAP) m = CAP;
    const int n0 = b << BSHIFT;
    const unsigned int* ap = arena + (size_t)b * CAP;
    for (int i = t; i < m; i += 512) {
        const unsigned int p = ap[i];
        const int dl = p >> 16;
        const int s  = p & 0xFFFFu;
        const int pos = atomicAdd(&lcnt[dl], 1);
        if (pos < MAXDEG) slotu[(size_t)(n0 + dl) * MAXDEG + pos] = (unsigned short)s;
    }
    __syncthreads();
    const int n = n0 + t;
    if (n < N_NODES) cnt[n] = lcnt[t];
}

// Wave per destination node (4/block). Score phase from f32 a_src/a_dst; main
// loop gathers bf16 x rows (128B/edge, ~2x L2 residency) + f32 accumulate.
__global__ __launch_bounds__(256) void aggregate_x_kernel(
        const int* __restrict__ cnt, const unsigned short* __restrict__ slotu,
        const float4* __restrict__ a_src4, const float4* __restrict__ a_dst4,
        const unsigned short* __restrict__ xb, unsigned short* __restrict__ yb) {
    __shared__ int    lsrc[4][64];
    __shared__ float4 lscs[4][64];
    const int w    = threadIdx.x >> 6;
    const int lane = threadIdx.x & 63;
    const int node = blockIdx.x * 4 + w;                    // 12500*4 = 50000 exact
    int deg = cnt[node];
    if (deg > MAXDEG) deg = MAXDEG;
    const size_t base = (size_t)node * MAXDEG;
    const float4 ad = a_dst4[node];

    // ---- score phase: lane handles slot `lane` ----
    int s = (lane < deg) ? (int)slotu[base + lane] : 0;
    float4 A = a_src4[s];
    float4 sc;
    if (lane < deg) {
        sc.x = lrelu_exp(A.x + ad.x); sc.y = lrelu_exp(A.y + ad.y);
        sc.z = lrelu_exp(A.z + ad.z); sc.w = lrelu_exp(A.w + ad.w);
    } else {
        sc = (float4){0.f, 0.f, 0.f, 0.f};
    }
    lsrc[w][lane] = s;
    lscs[w][lane] = sc;

    float4 ds = sc;                                         // butterfly sum (all lanes get it)
#pragma unroll
    for (int m = 1; m < 64; m <<= 1) {
        ds.x += __shfl_xor(ds.x, m, 64); ds.y += __shfl_xor(ds.y, m, 64);
        ds.z += __shfl_xor(ds.z, m, 64); ds.w += __shfl_xor(ds.w, m, 64);
    }
    float4 inv;
    inv.x = 1.f / (ds.x + EPS); inv.y = 1.f / (ds.y + EPS);
    inv.z = 1.f / (ds.z + EPS); inv.w = 1.f / (ds.w + EPS);

    // ---- gather/accumulate: lane = x-dim, bf16 source rows ----
    float4 acc = {0.f, 0.f, 0.f, 0.f};
    int e = 0;
    for (; e + 3 < deg; e += 4) {
        int s0 = lsrc[w][e + 0], s1 = lsrc[w][e + 1];
        int s2 = lsrc[w][e + 2], s3 = lsrc[w][e + 3];
        float4 c0 = lscs[w][e + 0], c1 = lscs[w][e + 1];
        float4 c2 = lscs[w][e + 2], c3 = lscs[w][e + 3];
        float x0 = bf2f(xb[(size_t)s0 * 64 + lane]);
        float x1 = bf2f(xb[(size_t)s1 * 64 + lane]);
        float x2 = bf2f(xb[(size_t)s2 * 64 + lane]);
        float x3 = bf2f(xb[(size_t)s3 * 64 + lane]);
        acc.x += x0 * c0.x + x1 * c1.x + x2 * c2.x + x3 * c3.x;
        acc.y += x0 * c0.y + x1 * c1.y + x2 * c2.y + x3 * c3.y;
        acc.z += x0 * c0.z + x1 * c1.z + x2 * c2.z + x3 * c3.z;
        acc.w += x0 * c0.w + x1 * c1.w + x2 * c2.w + x3 * c3.w;
    }
    for (; e < deg; ++e) {
        int se = lsrc[w][e];
        float4 ce = lscs[w][e];
        float xv = bf2f(xb[(size_t)se * 64 + lane]);
        acc.x += xv * ce.x; acc.y += xv * ce.y;
        acc.z += xv * ce.z; acc.w += xv * ce.w;
    }
    unsigned short* yp = yb + (size_t)node * 256 + lane;
    __builtin_nontemporal_store(f2bf(acc.x * inv.x), yp);       // don't evict xb
    __builtin_nontemporal_store(f2bf(acc.y * inv.y), yp + 64);
    __builtin_nontemporal_store(f2bf(acc.z * inv.z), yp + 128);
    __builtin_nontemporal_store(f2bf(acc.w * inv.w), yp + 192);
}

// out[n][c] = sum_k y[n][(c>>6)*64+k] * W[k][c] + bias[c], via bf16 MFMA.
// Block = 64 rows x 256 cols; W staged to LDS bf16 transposed + XOR swizzle.
__global__ __launch_bounds__(256) void gemm_out_kernel(
        const unsigned short* __restrict__ yb, const float* __restrict__ W,
        const float* __restrict__ bias, float* __restrict__ out) {
    __shared__ __align__(16) unsigned short Wt[256 * 64];   // 32 KB
    const int t = threadIdx.x;
    {
        const int c = t;
        for (int kg = 0; kg < 8; ++kg) {
            float4 lo, hi;
            lo.x = W[(kg * 8 + 0) * 256 + c]; lo.y = W[(kg * 8 + 1) * 256 + c];
            lo.z = W[(kg * 8 + 2) * 256 + c]; lo.w = W[(kg * 8 + 3) * 256 + c];
            hi.x = W[(kg * 8 + 4) * 256 + c]; hi.y = W[(kg * 8 + 5) * 256 + c];
            hi.z = W[(kg * 8 + 6) * 256 + c]; hi.w = W[(kg * 8 + 7) * 256 + c];
            *(short8*)&Wt[c * 64 + ((kg ^ (c & 7)) << 3)] = pack8(lo, hi);
        }
    }
    __syncthreads();

    const int wave = t >> 6, lane = t & 63;
    const int q = lane >> 4, mloc = lane & 15;
    const int rowbase = blockIdx.x * 64 + wave * 16;        // 782 blocks, tail guarded
    int arow = rowbase + mloc;
    if (arow > N_NODES - 1) arow = N_NODES - 1;

    short8 a0[4], a1[4];
#pragma unroll
    for (int h = 0; h < 4; ++h) {
        const unsigned short* yr = yb + (size_t)arow * 256 + h * 64;
        a0[h] = *(const short8*)&yr[q * 8];
        a1[h] = *(const short8*)&yr[32 + q * 8];
    }

    f32x4 acc[16];
#pragma unroll
    for (int n = 0; n < 16; ++n) acc[n] = (f32x4){0.f, 0.f, 0.f, 0.f};
#pragma unroll
    for (int n = 0; n < 16; ++n) {
        const int c = n * 16 + mloc;
        const int h = n >> 2;
        const unsigned short* rowp = &Wt[c * 64];
        short8 b0 = *(const short8*)&rowp[((q    ) ^ (c & 7)) << 3];
        short8 b1 = *(const short8*)&rowp[((4 + q) ^ (c & 7)) << 3];
        acc[n] = __builtin_amdgcn_mfma_f32_16x16x32_bf16(a0[h], b0, acc[n], 0, 0, 0);
        acc[n] = __builtin_amdgcn_mfma_f32_16x16x32_bf16(a1[h], b1, acc[n], 0, 0, 0);
    }

    float bv[16];
#pragma unroll
    for (int n = 0; n < 16; ++n) bv[n] = bias[n * 16 + mloc];

    const int orow = rowbase + q * 4;                       // C/D: col=lane&15, row=q*4+r
#pragma unroll
    for (int r = 0; r < 4; ++r) {
        if (orow + r < N_NODES) {
            float* op = out + (size_t)(orow + r) * 256 + mloc;
#pragma unroll
            for (int n = 0; n < 16; ++n) op[n * 16] = acc[n][r] + bv[n];
        }
    }
}

extern "C" void kernel_launch(void* const* d_in, const int* in_sizes, int n_in,
                              void* d_out, int out_size, void* d_ws, size_t ws_size,
                              hipStream_t stream) {
    const float* x       = (const float*)d_in[0];
    const int*   eidx    = (const int*)  d_in[1];
    const float* W       = (const float*)d_in[2];
    const float* att_src = (const float*)d_in[3];
    const float* att_dst = (const float*)d_in[4];
    const float* bias    = (const float*)d_in[5];
    float* out = (float*)d_out;

    unsigned short* yb = (unsigned short*)d_ws;         // 12.8M bf16 (25.6 MB)
    float* a_src = (float*)(yb + (size_t)N_NODES * HD); // 200K f32
    float* a_dst = a_src + N_NODES * 4;                 // 200K f32
    float* ws    = a_dst + N_NODES * 4;                 // 256 f32
    float* wd    = ws + 256;                            // 256 f32
    int*   cnt   = (int*)(wd + 256);                    // 50K int
    int*   gcnt  = cnt + N_NODES;                       // 98 int (padded to 128)
    unsigned int*   arena = (unsigned int*)(gcnt + 128);         // 98*10240 u32 (4.0 MB)
    unsigned short* slotu = (unsigned short*)(arena + NB * CAP); // 3.2M u16 (6.4 MB)
    unsigned short* xb    = slotu + (size_t)N_NODES * MAXDEG;    // 3.2M u16 (6.4 MB)

    hipMemsetAsync(gcnt, 0, 128 * sizeof(int), stream);
    prep_kernel<<<1, 256, 0, stream>>>(W, att_src, att_dst, ws, wd);
    bin_logit_kernel<<<ABLK, 256, 0, stream>>>(
        x, (const float4*)ws, (const float4*)wd, eidx, gcnt, arena,
        (float4*)a_src, (float4*)a_dst, xb);
    ell_build_kernel<<<NB, 512, 0, stream>>>(gcnt, arena, cnt, slotu);
    aggregate_x_kernel<<<N_NODES / 4, 256, 0, stream>>>(
        cnt, slotu, (const float4*)a_src, (const float4*)a_dst, xb, yb);
    gemm_out_kernel<<<(N_NODES + 63) / 64, 256, 0, stream>>>(yb, W, bias, out);
}

// Round 3
// 167.379 us; speedup vs baseline: 1.0240x; 1.0240x over previous
//
#include <hip/hip_runtime.h>

#define N_NODES 50000
#define N_EDGES 800000
#define E_TOT   850000          // edges + self loops
#define HD      256             // HEADS*HEAD_DIM
#define MAXDEG  64              // max in-degree ~45 (Poisson(17), fixed seed); P(>=64)~1e-19
#define NEG_SLOPE 0.2f
#define EPS 1e-16f

// ---- dst-bucket binning (kills the 16x scattered-write amplification) ----
#define NB     98               // buckets of 512 nodes (49999>>9 = 97)
#define BSHIFT 9
#define CAP    10240            // per-bucket arena cap: E[8673] + ~16 sigma
#define ABLK   392              // binning blocks
#define EPB    2304             // edges per block (9/thread); 392*2304 >= 850000

typedef __attribute__((ext_vector_type(8))) short short8;
typedef __attribute__((ext_vector_type(4))) float f32x4;

__device__ __forceinline__ unsigned short f2bf(float f) {   // round-to-nearest-even
    union { float f; unsigned int i; } c; c.f = f;
    unsigned int r = 0x7fffu + ((c.i >> 16) & 1u);
    return (unsigned short)((c.i + r) >> 16);
}
__device__ __forceinline__ float bf2f(unsigned short u) {
    union { unsigned int i; float f; } c; c.i = ((unsigned int)u) << 16;
    return c.f;
}
__device__ __forceinline__ short8 pack8(float4 a, float4 b) {
    short8 r;
    r[0] = (short)f2bf(a.x); r[1] = (short)f2bf(a.y);
    r[2] = (short)f2bf(a.z); r[3] = (short)f2bf(a.w);
    r[4] = (short)f2bf(b.x); r[5] = (short)f2bf(b.y);
    r[6] = (short)f2bf(b.z); r[7] = (short)f2bf(b.w);
    return r;
}
__device__ __forceinline__ float lrelu_exp(float v) {
    v = (v < 0.f) ? v * NEG_SLOPE : v;
    return __expf(v);
}

// ws[k][head] = sum_j W[k][head*64+j]*att_src[head][j]  (attention folded into
// x-space). Also zeroes gcnt (replaces a separate memset dispatch).
__global__ __launch_bounds__(256) void prep_kernel(
        const float* __restrict__ W, const float* __restrict__ att_src,
        const float* __restrict__ att_dst, float* __restrict__ ws, float* __restrict__ wd,
        int* __restrict__ gcnt) {
    const int t = threadIdx.x, head = t >> 6, k = t & 63;
    if (t < 128) gcnt[t] = 0;
    const float* wrow = W + k * 256 + head * 64;
    const float* as = att_src + head * 64;
    const float* adv = att_dst + head * 64;
    float s = 0.f, d = 0.f;
#pragma unroll 8
    for (int j = 0; j < 64; ++j) { s += wrow[j] * as[j]; d += wrow[j] * adv[j]; }
    ws[k * 4 + head] = s;
    wd[k * 4 + head] = d;
}

// Phase A: bin edges by dst>>9 into per-bucket arenas (L2-merged contiguous
// windows). Per-WAVE histograms + cursors: 4x less same-address LDS-atomic
// serialization than a single block-level histogram. Blocks 0..195 also
// compute per-node logits AND emit xb (bf16 x) for the 128B/edge gather.
__global__ __launch_bounds__(256) void bin_logit_kernel(
        const float* __restrict__ x,
        const float4* __restrict__ ws4, const float4* __restrict__ wd4,
        const int* __restrict__ eidx,
        int* __restrict__ gcnt, unsigned int* __restrict__ arena,
        float4* __restrict__ a_src4, float4* __restrict__ a_dst4,
        unsigned short* __restrict__ xb) {
    __shared__ int hist[4][NB];
    __shared__ int abase[4][NB];
    const int t = threadIdx.x;
    const int w = t >> 6;
    const int e0 = blockIdx.x * EPB;
    for (int i = t; i < 4 * NB; i += 256) ((int*)hist)[i] = 0;
    __syncthreads();

    // pass 1: per-wave dst histogram
#pragma unroll
    for (int k = 0; k < EPB / 256; ++k) {
        const int g = e0 + k * 256 + t;
        if (g < E_TOT) {
            const int d = (g < N_EDGES) ? eidx[N_EDGES + g] : g - N_EDGES;
            atomicAdd(&hist[w][d >> BSHIFT], 1);
        }
    }
    __syncthreads();
    if (t < NB) {
        const int c0 = hist[0][t], c1 = hist[1][t], c2 = hist[2][t], c3 = hist[3][t];
        const int tot = c0 + c1 + c2 + c3;
        const int base = tot ? atomicAdd(&gcnt[t], tot) : 0;
        abase[0][t] = base;
        abase[1][t] = base + c0;
        abase[2][t] = base + c0 + c1;
        abase[3][t] = base + c0 + c1 + c2;
        hist[0][t] = 0; hist[1][t] = 0; hist[2][t] = 0; hist[3][t] = 0;
    }
    __syncthreads();

    // pass 2: scatter packed (src | dst_local<<16) pairs via per-wave cursors
#pragma unroll
    for (int k = 0; k < EPB / 256; ++k) {
        const int g = e0 + k * 256 + t;
        if (g < E_TOT) {
            int s, d;
            if (g < N_EDGES) { s = eidx[g]; d = eidx[N_EDGES + g]; }
            else             { s = d = g - N_EDGES; }
            const int b = d >> BSHIFT;
            const int pos = abase[w][b] + atomicAdd(&hist[w][b], 1);
            if (pos < CAP)
                arena[b * CAP + pos] =
                    (unsigned int)s | ((unsigned int)(d & 511) << 16);
        }
    }

    // per-node logits + bf16 x emission (x row already in registers)
    const int g = blockIdx.x * 256 + t;
    if (g < N_NODES) {
        const float4* xr = (const float4*)(x + (size_t)g * 64);
        float4 vs = {0.f, 0.f, 0.f, 0.f};
        float4 vd = {0.f, 0.f, 0.f, 0.f};
#pragma unroll 4
        for (int kk = 0; kk < 16; kk += 2) {
            float4 xv0 = xr[kk];
            float4 xv1 = xr[kk + 1];
            *(short8*)&xb[(size_t)g * 64 + kk * 4] = pack8(xv0, xv1);
#pragma unroll
            for (int j = 0; j < 8; ++j) {
                const float4 xv = (j < 4) ? xv0 : xv1;
                const int jj = j & 3;
                const float xj = jj == 0 ? xv.x : jj == 1 ? xv.y : jj == 2 ? xv.z : xv.w;
                const float4 w1 = ws4[(kk + (j >> 2)) * 4 + jj];
                const float4 w2 = wd4[(kk + (j >> 2)) * 4 + jj];
                vs.x += xj * w1.x; vs.y += xj * w1.y; vs.z += xj * w1.z; vs.w += xj * w1.w;
                vd.x += xj * w2.x; vd.y += xj * w2.y; vd.z += xj * w2.z; vd.w += xj * w2.w;
            }
        }
        a_src4[g] = vs;
        a_dst4[g] = vd;
    }
}

// Phase B: block b exclusively owns nodes [b*512, b*512+512) -> ELL build with
// LDS counters; scattered ushort writes stay in a private 64KB L2-hot window.
// 1024 threads + uint4 arena reads: more loads in flight on a 98-block grid.
__global__ __launch_bounds__(1024) void ell_build_kernel(
        const int* __restrict__ gcnt, const unsigned int* __restrict__ arena,
        int* __restrict__ cnt, unsigned short* __restrict__ slotu) {
    __shared__ int lcnt[512];
    const int t = threadIdx.x;
    const int b = blockIdx.x;
    if (t < 512) lcnt[t] = 0;
    __syncthreads();
    int m = gcnt[b]; if (m > CAP) m = CAP;
    const int n0 = b << BSHIFT;
    const unsigned int* ap = arena + (size_t)b * CAP;
    const uint4* ap4 = (const uint4*)ap;
    const int m4 = m >> 2;
    for (int i = t; i < m4; i += 1024) {
        const uint4 p4 = ap4[i];
#pragma unroll
        for (int j = 0; j < 4; ++j) {
            const unsigned int p = j == 0 ? p4.x : j == 1 ? p4.y : j == 2 ? p4.z : p4.w;
            const int dl = p >> 16;
            const int s  = p & 0xFFFFu;
            const int pos = atomicAdd(&lcnt[dl], 1);
            if (pos < MAXDEG) slotu[(size_t)(n0 + dl) * MAXDEG + pos] = (unsigned short)s;
        }
    }
    for (int i = (m4 << 2) + t; i < m; i += 1024) {
        const unsigned int p = ap[i];
        const int dl = p >> 16;
        const int s  = p & 0xFFFFu;
        const int pos = atomicAdd(&lcnt[dl], 1);
        if (pos < MAXDEG) slotu[(size_t)(n0 + dl) * MAXDEG + pos] = (unsigned short)s;
    }
    __syncthreads();
    if (t < 512) {
        const int n = n0 + t;
        if (n < N_NODES) cnt[n] = lcnt[t];
    }
}

// Wave per destination node (4/block). Score phase from f32 a_src/a_dst; main
// loop gathers bf16 x rows (128B/edge, ~2x L2 residency) + f32 accumulate.
// Plain yb stores (L3-resident for the GEMM's immediate re-read).
__global__ __launch_bounds__(256) void aggregate_x_kernel(
        const int* __restrict__ cnt, const unsigned short* __restrict__ slotu,
        const float4* __restrict__ a_src4, const float4* __restrict__ a_dst4,
        const unsigned short* __restrict__ xb, unsigned short* __restrict__ yb) {
    __shared__ int    lsrc[4][64];
    __shared__ float4 lscs[4][64];
    const int w    = threadIdx.x >> 6;
    const int lane = threadIdx.x & 63;
    const int node = blockIdx.x * 4 + w;                    // 12500*4 = 50000 exact
    int deg = cnt[node];
    if (deg > MAXDEG) deg = MAXDEG;
    const size_t base = (size_t)node * MAXDEG;
    const float4 ad = a_dst4[node];

    // ---- score phase: lane handles slot `lane` ----
    int s = (lane < deg) ? (int)slotu[base + lane] : 0;
    float4 A = a_src4[s];
    float4 sc;
    if (lane < deg) {
        sc.x = lrelu_exp(A.x + ad.x); sc.y = lrelu_exp(A.y + ad.y);
        sc.z = lrelu_exp(A.z + ad.z); sc.w = lrelu_exp(A.w + ad.w);
    } else {
        sc = (float4){0.f, 0.f, 0.f, 0.f};
    }
    lsrc[w][lane] = s;
    lscs[w][lane] = sc;

    float4 ds = sc;                                         // butterfly sum (all lanes get it)
#pragma unroll
    for (int m = 1; m < 64; m <<= 1) {
        ds.x += __shfl_xor(ds.x, m, 64); ds.y += __shfl_xor(ds.y, m, 64);
        ds.z += __shfl_xor(ds.z, m, 64); ds.w += __shfl_xor(ds.w, m, 64);
    }
    float4 inv;
    inv.x = 1.f / (ds.x + EPS); inv.y = 1.f / (ds.y + EPS);
    inv.z = 1.f / (ds.z + EPS); inv.w = 1.f / (ds.w + EPS);

    // ---- gather/accumulate: lane = x-dim, bf16 source rows ----
    float4 acc = {0.f, 0.f, 0.f, 0.f};
    int e = 0;
    for (; e + 3 < deg; e += 4) {
        int s0 = lsrc[w][e + 0], s1 = lsrc[w][e + 1];
        int s2 = lsrc[w][e + 2], s3 = lsrc[w][e + 3];
        float4 c0 = lscs[w][e + 0], c1 = lscs[w][e + 1];
        float4 c2 = lscs[w][e + 2], c3 = lscs[w][e + 3];
        float x0 = bf2f(xb[(size_t)s0 * 64 + lane]);
        float x1 = bf2f(xb[(size_t)s1 * 64 + lane]);
        float x2 = bf2f(xb[(size_t)s2 * 64 + lane]);
        float x3 = bf2f(xb[(size_t)s3 * 64 + lane]);
        acc.x += x0 * c0.x + x1 * c1.x + x2 * c2.x + x3 * c3.x;
        acc.y += x0 * c0.y + x1 * c1.y + x2 * c2.y + x3 * c3.y;
        acc.z += x0 * c0.z + x1 * c1.z + x2 * c2.z + x3 * c3.z;
        acc.w += x0 * c0.w + x1 * c1.w + x2 * c2.w + x3 * c3.w;
    }
    for (; e < deg; ++e) {
        int se = lsrc[w][e];
        float4 ce = lscs[w][e];
        float xv = bf2f(xb[(size_t)se * 64 + lane]);
        acc.x += xv * ce.x; acc.y += xv * ce.y;
        acc.z += xv * ce.z; acc.w += xv * ce.w;
    }
    unsigned short* yp = yb + (size_t)node * 256 + lane;
    yp[  0] = f2bf(acc.x * inv.x);
    yp[ 64] = f2bf(acc.y * inv.y);
    yp[128] = f2bf(acc.z * inv.z);
    yp[192] = f2bf(acc.w * inv.w);
}

// out[n][c] = sum_k y[n][(c>>6)*64+k] * W[k][c] + bias[c], via bf16 MFMA.
// Block = 64 rows x 256 cols; W staged to LDS bf16 transposed + XOR swizzle.
__global__ __launch_bounds__(256) void gemm_out_kernel(
        const unsigned short* __restrict__ yb, const float* __restrict__ W,
        const float* __restrict__ bias, float* __restrict__ out) {
    __shared__ __align__(16) unsigned short Wt[256 * 64];   // 32 KB
    const int t = threadIdx.x;
    {
        const int c = t;
        for (int kg = 0; kg < 8; ++kg) {
            float4 lo, hi;
            lo.x = W[(kg * 8 + 0) * 256 + c]; lo.y = W[(kg * 8 + 1) * 256 + c];
            lo.z = W[(kg * 8 + 2) * 256 + c]; lo.w = W[(kg * 8 + 3) * 256 + c];
            hi.x = W[(kg * 8 + 4) * 256 + c]; hi.y = W[(kg * 8 + 5) * 256 + c];
            hi.z = W[(kg * 8 + 6) * 256 + c]; hi.w = W[(kg * 8 + 7) * 256 + c];
            *(short8*)&Wt[c * 64 + ((kg ^ (c & 7)) << 3)] = pack8(lo, hi);
        }
    }
    __syncthreads();

    const int wave = t >> 6, lane = t & 63;
    const int q = lane >> 4, mloc = lane & 15;
    const int rowbase = blockIdx.x * 64 + wave * 16;        // 782 blocks, tail guarded
    int arow = rowbase + mloc;
    if (arow > N_NODES - 1) arow = N_NODES - 1;

    short8 a0[4], a1[4];
#pragma unroll
    for (int h = 0; h < 4; ++h) {
        const unsigned short* yr = yb + (size_t)arow * 256 + h * 64;
        a0[h] = *(const short8*)&yr[q * 8];
        a1[h] = *(const short8*)&yr[32 + q * 8];
    }

    f32x4 acc[16];
#pragma unroll
    for (int n = 0; n < 16; ++n) acc[n] = (f32x4){0.f, 0.f, 0.f, 0.f};
#pragma unroll
    for (int n = 0; n < 16; ++n) {
        const int c = n * 16 + mloc;
        const int h = n >> 2;
        const unsigned short* rowp = &Wt[c * 64];
        short8 b0 = *(const short8*)&rowp[((q    ) ^ (c & 7)) << 3];
        short8 b1 = *(const short8*)&rowp[((4 + q) ^ (c & 7)) << 3];
        acc[n] = __builtin_amdgcn_mfma_f32_16x16x32_bf16(a0[h], b0, acc[n], 0, 0, 0);
        acc[n] = __builtin_amdgcn_mfma_f32_16x16x32_bf16(a1[h], b1, acc[n], 0, 0, 0);
    }

    float bv[16];
#pragma unroll
    for (int n = 0; n < 16; ++n) bv[n] = bias[n * 16 + mloc];

    const int orow = rowbase + q * 4;                       // C/D: col=lane&15, row=q*4+r
#pragma unroll
    for (int r = 0; r < 4; ++r) {
        if (orow + r < N_NODES) {
            float* op = out + (size_t)(orow + r) * 256 + mloc;
#pragma unroll
            for (int n = 0; n < 16; ++n) op[n * 16] = acc[n][r] + bv[n];
        }
    }
}

extern "C" void kernel_launch(void* const* d_in, const int* in_sizes, int n_in,
                              void* d_out, int out_size, void* d_ws, size_t ws_size,
                              hipStream_t stream) {
    const float* x       = (const float*)d_in[0];
    const int*   eidx    = (const int*)  d_in[1];
    const float* W       = (const float*)d_in[2];
    const float* att_src = (const float*)d_in[3];
    const float* att_dst = (const float*)d_in[4];
    const float* bias    = (const float*)d_in[5];
    float* out = (float*)d_out;

    unsigned short* yb = (unsigned short*)d_ws;         // 12.8M bf16 (25.6 MB)
    float* a_src = (float*)(yb + (size_t)N_NODES * HD); // 200K f32
    float* a_dst = a_src + N_NODES * 4;                 // 200K f32
    float* ws    = a_dst + N_NODES * 4;                 // 256 f32
    float* wd    = ws + 256;                            // 256 f32
    int*   cnt   = (int*)(wd + 256);                    // 50K int
    int*   gcnt  = cnt + N_NODES;                       // 98 int (padded to 128)
    unsigned int*   arena = (unsigned int*)(gcnt + 128);         // 98*10240 u32 (4.0 MB)
    unsigned short* slotu = (unsigned short*)(arena + NB * CAP); // 3.2M u16 (6.4 MB)
    unsigned short* xb    = slotu + (size_t)N_NODES * MAXDEG;    // 3.2M u16 (6.4 MB)

    prep_kernel<<<1, 256, 0, stream>>>(W, att_src, att_dst, ws, wd, gcnt);
    bin_logit_kernel<<<ABLK, 256, 0, stream>>>(
        x, (const float4*)ws, (const float4*)wd, eidx, gcnt, arena,
        (float4*)a_src, (float4*)a_dst, xb);
    ell_build_kernel<<<NB, 1024, 0, stream>>>(gcnt, arena, cnt, slotu);
    aggregate_x_kernel<<<N_NODES / 4, 256, 0, stream>>>(
        cnt, slotu, (const float4*)a_src, (const float4*)a_dst, xb, yb);
    gemm_out_kernel<<<(N_NODES + 63) / 64, 256, 0, stream>>>(yb, W, bias, out);
}